// Round 3
// baseline (461.787 us; speedup 1.0000x reference)
//
#include <hip/hip_runtime.h>

// HashEmbedding (Instant-NGP hash grid), MI355X gfx950.
// Round 3: one level per XCD per phase (2 phases), level-major workspace,
// streaming transpose. Bottleneck model: 1 L1 transaction/cycle/CU on
// 134M divergent 8B gathers -> floor ~218us for the gather work.

#define NLVL 16
#define TMASK ((1u << 19) - 1u)
#define P1 2654435761u
#define P2 805459861u

__constant__ float c_res[NLVL] = {16.f, 20.f, 25.f, 32.f, 40.f, 50.f, 64.f, 80.f,
                                  101.f, 128.f, 161.f, 203.f, 256.f, 322.f, 406.f, 512.f};

__device__ __forceinline__ float2 level_interp(float xn0, float xn1, float xn2,
                                               float r, const float2* __restrict__ tab)
{
    const float s0 = xn0 * r;
    const float s1 = xn1 * r;
    const float s2 = xn2 * r;
    const float f0 = floorf(s0);
    const float f1 = floorf(s1);
    const float f2 = floorf(s2);
    const float w0 = s0 - f0;
    const float w1 = s1 - f1;
    const float w2 = s2 - f2;
    const unsigned v0 = (unsigned)(int)f0;
    const unsigned v1 = (unsigned)(int)f1;
    const unsigned v2 = (unsigned)(int)f2;

    const unsigned ax0 = v0;
    const unsigned ax1 = v0 + 1u;
    const unsigned bx0 = v1 * P1;
    const unsigned bx1 = (v1 + 1u) * P1;
    const unsigned cx0 = v2 * P2;
    const unsigned cx1 = (v2 + 1u) * P2;

    const float2 e0 = tab[(ax0 ^ bx0 ^ cx0) & TMASK];
    const float2 e1 = tab[(ax0 ^ bx0 ^ cx1) & TMASK];
    const float2 e2 = tab[(ax0 ^ bx1 ^ cx0) & TMASK];
    const float2 e3 = tab[(ax0 ^ bx1 ^ cx1) & TMASK];
    const float2 e4 = tab[(ax1 ^ bx0 ^ cx0) & TMASK];
    const float2 e5 = tab[(ax1 ^ bx0 ^ cx1) & TMASK];
    const float2 e6 = tab[(ax1 ^ bx1 ^ cx0) & TMASK];
    const float2 e7 = tab[(ax1 ^ bx1 ^ cx1) & TMASK];

    const float omx = 1.0f - w0;
    const float omy = 1.0f - w1;
    const float omz = 1.0f - w2;

    const float c00x = e0.x * omx + e4.x * w0;
    const float c00y = e0.y * omx + e4.y * w0;
    const float c01x = e1.x * omx + e5.x * w0;
    const float c01y = e1.y * omx + e5.y * w0;
    const float c10x = e2.x * omx + e6.x * w0;
    const float c10y = e2.y * omx + e6.y * w0;
    const float c11x = e3.x * omx + e7.x * w0;
    const float c11y = e3.y * omx + e7.y * w0;

    const float c0x = c00x * omy + c10x * w1;
    const float c0y = c00y * omy + c10y * w1;
    const float c1x = c01x * omy + c11x * w1;
    const float c1y = c01y * omy + c11y * w1;

    float2 o;
    o.x = c0x * omz + c1x * w2;
    o.y = c0y * omz + c1y * w2;
    return o;
}

// ---- Kernel 1: gather; one level per block; XCD q sees only level q (phase A,
// blocks 0..32767) then level q+8 (phase B, blocks 32768..65535). ----
__global__ __launch_bounds__(256)
void k_gather_lvl(const float* __restrict__ x,
                  const float* __restrict__ tables,
                  float2* __restrict__ ws)
{
    const unsigned b = blockIdx.x;
    const int lvl = (int)((b & 7u) + ((b >> 15) << 3));   // 0..15, block-uniform
    const int p = (int)((((b & 32767u) >> 3) << 8) + threadIdx.x);

    const float xn0 = (x[3 * p + 0] + 1.0f) * 0.5f;
    const float xn1 = (x[3 * p + 1] + 1.0f) * 0.5f;
    const float xn2 = (x[3 * p + 2] + 1.0f) * 0.5f;

    const float2* tab = (const float2*)tables + ((size_t)lvl << 19);
    const float2 o = level_interp(xn0, xn1, xn2, c_res[lvl], tab);

    ws[((size_t)lvl << 20) + p] = o;   // level-major slab, 8B coalesced
}

// ---- Kernel 2: streaming transpose ws[l][p] -> out[p][2l..2l+1] ----
__global__ __launch_bounds__(256)
void k_transpose(const float2* __restrict__ ws,
                 float4* __restrict__ out)
{
    const int p = blockIdx.x * 256 + threadIdx.x;

    float o[2 * NLVL];
#pragma unroll
    for (int l = 0; l < NLVL; ++l) {
        const float2 v = ws[((size_t)l << 20) + p];
        o[2 * l + 0] = v.x;
        o[2 * l + 1] = v.y;
    }

    float4* op = out + (size_t)p * 8;
#pragma unroll
    for (int q = 0; q < 8; ++q)
        op[q] = make_float4(o[4 * q], o[4 * q + 1], o[4 * q + 2], o[4 * q + 3]);
}

// ---- Fallback: single-kernel version (unexpected n or small ws) ----
__global__ __launch_bounds__(256)
void hash_embed_fallback(const float* __restrict__ x,
                         const float* __restrict__ tables,
                         float* __restrict__ out,
                         int n)
{
    const int p = blockIdx.x * 256 + threadIdx.x;
    if (p >= n) return;

    const float xn0 = (x[3 * p + 0] + 1.0f) * 0.5f;
    const float xn1 = (x[3 * p + 1] + 1.0f) * 0.5f;
    const float xn2 = (x[3 * p + 2] + 1.0f) * 0.5f;

    float o[2 * NLVL];
#pragma unroll
    for (int l = 0; l < NLVL; ++l) {
        const float2* tab = (const float2*)tables + ((size_t)l << 19);
        const float2 v = level_interp(xn0, xn1, xn2, c_res[l], tab);
        o[2 * l + 0] = v.x;
        o[2 * l + 1] = v.y;
    }

    float4* op = (float4*)(out + (size_t)p * 32);
#pragma unroll
    for (int q = 0; q < 8; ++q)
        op[q] = make_float4(o[4 * q], o[4 * q + 1], o[4 * q + 2], o[4 * q + 3]);
}

extern "C" void kernel_launch(void* const* d_in, const int* in_sizes, int n_in,
                              void* d_out, int out_size, void* d_ws, size_t ws_size,
                              hipStream_t stream) {
    const float* x = (const float*)d_in[0];
    const float* tables = (const float*)d_in[1];
    float* out = (float*)d_out;
    const int n = in_sizes[0] / 3;                                   // 1048576
    const size_t ws_needed = (size_t)NLVL * (size_t)n * sizeof(float2);  // 128 MB

    if (n == (1 << 20) && ws_size >= ws_needed) {
        k_gather_lvl<<<NLVL * 4096, 256, 0, stream>>>(x, tables, (float2*)d_ws);
        k_transpose<<<4096, 256, 0, stream>>>((const float2*)d_ws, (float4*)out);
    } else {
        hash_embed_fallback<<<(n + 255) / 256, 256, 0, stream>>>(x, tables, out, n);
    }
}